// Round 13
// baseline (1725.260 us; speedup 1.0000x reference)
//
#include <hip/hip_runtime.h>

typedef __bf16 bf16_t;
typedef __bf16 bf16x4 __attribute__((ext_vector_type(4)));
typedef __bf16 bf16x8 __attribute__((ext_vector_type(8)));
typedef float f32x16 __attribute__((ext_vector_type(16)));

#define DD 300
#define LDP 320
#define EST 304   // packed stride for persistent CSR-ordered edge features
#define TLD 328   // padded LDS stride for the fused g/t-tile
#define WSLOT (LDP * LDP)

struct Src12 { const float* p[12]; };

// async global->LDS, 16B per lane (wave-uniform LDS base + lane*16)
__device__ __forceinline__ void gload16(const bf16_t* g, bf16_t* l) {
  __builtin_amdgcn_global_load_lds(
      (const __attribute__((address_space(1))) void*)g,
      (__attribute__((address_space(3))) void*)l, 16, 0, 0);
}

// wt[m][n*LDP + k] = W_m[k*DD + n], zero-padded to 320x320 (n-major, k-contig)
__global__ void prep_wt_all(Src12 s, bf16_t* __restrict__ wt) {
  int m = blockIdx.y;
  int idx = blockIdx.x * 256 + threadIdx.x;
  if (idx >= WSLOT) return;
  int n = idx / LDP, k = idx - n * LDP;
  float v = 0.f;
  if (n < DD && k < DD) v = s.p[m][(long)k * DD + n];
  wt[(size_t)m * WSLOT + idx] = (bf16_t)v;
}

__global__ void prep_wt_head(const float* __restrict__ ah_w, const float* __restrict__ ch_w,
                             bf16_t* __restrict__ wt) {
  int idx = blockIdx.x * 256 + threadIdx.x;
  if (idx >= WSLOT) return;
  int n = idx / LDP, k = idx - n * LDP;
  float v = 0.f;
  if (k < DD) {
    if (n < 87) v = ah_w[(long)k * 87 + n];
    else if (n < 93) v = ch_w[(long)k * 6 + (n - 87)];
  }
  wt[idx] = (bf16_t)v;
}

enum { MODE_F32S = 0, MODE_BF16_RELU = 1, MODE_BF16 = 2, MODE_EMB = 3, MODE_HEAD = 4,
       MODE_BF16S = 5, MODE_EPERM = 6, MODE_EBF16 = 7 };

// ---------------------------------------------------------------------------
// gemm2_k: single-buffered 64x320 GEMM — retained for fallback use.
// ---------------------------------------------------------------------------
template<int MODE>
__global__ __launch_bounds__(256, 3)
void gemm2_k(const bf16_t* Av, const bf16_t* __restrict__ Wt,
             const float* __restrict__ bias, void* outv, int M,
             const int* __restrict__ z, const float* __restrict__ emb,
             float* __restrict__ out2, const float* __restrict__ bias2)
{
  __shared__ bf16_t As2[64 * 32];
  __shared__ bf16_t Bs2[320 * 32];
  __shared__ float  red[2 * 320];

  const int tid = threadIdx.x;
  const int wave = tid >> 6;
  const int lane = tid & 63;
  const int lhalf = lane >> 5;
  const int l31 = lane & 31;
  const int m0 = blockIdx.x * 64;

  const int lr = lane >> 2;
  const int lu = lane & 3;

  const int ar = wave * 16 + lr;
  const int au = lu ^ ((ar >> 1) & 3);
  int arow = m0 + ar; if (arow >= M) arow = M - 1;
  const bf16_t* asrc = Av + (size_t)arow * LDP + au * 8;

  const bf16_t* bsrc[5];
  #pragma unroll
  for (int c = 0; c < 5; c++) {
    int q = wave * 5 + c;
    int bn = q * 16 + lr;
    int bu = lu ^ ((bn >> 1) & 3);
    bsrc[c] = Wt + (size_t)bn * LDP + bu * 8;
  }

  f32x16 acc[5] = {};

  for (int k0 = 0; k0 < LDP; k0 += 32) {
    gload16(asrc + k0, As2 + wave * 512);
    #pragma unroll
    for (int c = 0; c < 5; c++)
      gload16(bsrc[c] + k0, Bs2 + (wave * 5 + c) * 512);
    __syncthreads();
    #pragma unroll
    for (int ks = 0; ks < 2; ks++) {
      const int j0 = ks * 2 + lhalf;
      const int ra = (wave & 1) * 32 + l31;
      bf16x8 af = *(const bf16x8*)&As2[ra * 32 + ((j0 ^ ((ra >> 1) & 3)) * 8)];
      #pragma unroll
      for (int cf = 0; cf < 5; cf++) {
        const int bn = (wave >> 1) * 160 + cf * 32 + l31;
        bf16x8 bv = *(const bf16x8*)&Bs2[bn * 32 + ((j0 ^ ((bn >> 1) & 3)) * 8)];
        acc[cf] = __builtin_amdgcn_mfma_f32_32x32x16_bf16(af, bv, acc[cf], 0, 0, 0);
      }
    }
    __syncthreads();
  }

  const int colb = (wave >> 1) * 160;
  float s1[5], s2[5];
  #pragma unroll
  for (int i = 0; i < 5; i++) { s1[i] = 0.f; s2[i] = 0.f; }

  const int rowb = m0 + (wave & 1) * 32 + 4 * lhalf;
  #pragma unroll
  for (int cf = 0; cf < 5; cf++) {
    const int col = colb + cf * 32 + l31;
    float bv;
    if constexpr (MODE == MODE_HEAD) {
      bv = (col < 87) ? bias[col] : (col < 93 ? bias2[col - 87] : 0.f);
    } else {
      bv = (col < DD) ? bias[col] : 0.f;
    }
    f32x16 v = acc[cf];
    #pragma unroll
    for (int r = 0; r < 16; r++) {
      const int row = rowb + (r & 3) + 8 * (r >> 2);
      if (row >= M) continue;
      float val = v[r] + bv;
      if constexpr (MODE == MODE_F32S) {
        ((float*)outv)[(size_t)row * LDP + col] = val;
        s1[cf] += val; s2[cf] += val * val;
      } else if constexpr (MODE == MODE_BF16S) {
        ((bf16_t*)outv)[(size_t)row * LDP + col] = (bf16_t)val;
        s1[cf] += val; s2[cf] += val * val;
      } else if constexpr (MODE == MODE_BF16_RELU) {
        ((bf16_t*)outv)[(size_t)row * LDP + col] = (bf16_t)fmaxf(val, 0.f);
      } else if constexpr (MODE == MODE_BF16) {
        ((bf16_t*)outv)[(size_t)row * LDP + col] = (bf16_t)val;
      } else if constexpr (MODE == MODE_EPERM) {
        if (col < EST)
          ((bf16_t*)outv)[(size_t)z[row] * EST + col] = (bf16_t)val;
      } else if constexpr (MODE == MODE_EMB) {
        float add = (col < DD) ? emb[(size_t)z[row] * DD + col] : 0.f;
        ((bf16_t*)outv)[(size_t)row * LDP + col] = (bf16_t)(val + add);
      } else {  // MODE_HEAD
        if (col < 87) ((float*)outv)[(size_t)row * 87 + col] = val;
        else if (col < 93) out2[(size_t)row * 6 + (col - 87)] = val;
      }
    }
  }

  if constexpr (MODE == MODE_F32S || MODE == MODE_BF16S) {
    float t1[5], t2[5];
    #pragma unroll
    for (int cf = 0; cf < 5; cf++) {
      t1[cf] = s1[cf] + __shfl_down(s1[cf], 32);
      t2[cf] = s2[cf] + __shfl_down(s2[cf], 32);
    }
    if ((wave & 1) == 0 && lhalf == 0) {
      #pragma unroll
      for (int cf = 0; cf < 5; cf++) {
        const int col = colb + cf * 32 + l31;
        red[col] = t1[cf];
        red[320 + col] = t2[cf];
      }
    }
    __syncthreads();
    if ((wave & 1) == 1 && lhalf == 0) {
      #pragma unroll
      for (int cf = 0; cf < 5; cf++) {
        const int col = colb + cf * 32 + l31;
        if (col < DD) {
          atomicAdd(&out2[col], t1[cf] + red[col]);
          atomicAdd(&out2[LDP + col], t2[cf] + red[320 + col]);
        }
      }
    }
  }
}

// ---------------------------------------------------------------------------
// gemm_hd: HEAD GEMM with fused relu(BN(u)) A-generation (r12-proven).
// ---------------------------------------------------------------------------
__global__ __launch_bounds__(256, 3)
void gemm_hd(const bf16_t* __restrict__ U, const float* __restrict__ ab,
             const bf16_t* __restrict__ Wt, const float* __restrict__ bias,
             float* __restrict__ out, int M, float* __restrict__ out2,
             const float* __restrict__ bias2)
{
  __shared__ bf16_t As2[64 * 32];
  __shared__ bf16_t Bs2[320 * 32];

  const int tid = threadIdx.x;
  const int wave = tid >> 6;
  const int lane = tid & 63;
  const int lhalf = lane >> 5;
  const int l31 = lane & 31;
  const int m0 = blockIdx.x * 64;

  const int lr = lane >> 2;
  const int lu = lane & 3;

  const int ar = wave * 16 + lr;
  const int au = lu ^ ((ar >> 1) & 3);
  int arow = m0 + ar; if (arow >= M) arow = M - 1;

  const bf16_t* bsrc[5];
  #pragma unroll
  for (int c = 0; c < 5; c++) {
    int q = wave * 5 + c;
    int bn = q * 16 + lr;
    int bu = lu ^ ((bn >> 1) & 3);
    bsrc[c] = Wt + (size_t)bn * LDP + bu * 8;
  }

  f32x16 acc[5] = {};

  for (int k0 = 0; k0 < LDP; k0 += 32) {
    {
      const int cb = k0 + au * 8;
      bf16x8 uv = *(const bf16x8*)(U + (size_t)arow * LDP + cb);
      bf16x8 v;
      #pragma unroll
      for (int j = 0; j < 8; j++) {
        const int cc = cb + j;
        float x = 0.f;
        if (cc < DD) x = fmaxf((float)uv[j] * ab[cc] + ab[LDP + cc], 0.f);
        v[j] = (bf16_t)x;
      }
      *(bf16x8*)&As2[ar * 32 + lu * 8] = v;
    }
    #pragma unroll
    for (int c = 0; c < 5; c++)
      gload16(bsrc[c] + k0, Bs2 + (wave * 5 + c) * 512);
    __syncthreads();
    #pragma unroll
    for (int ks = 0; ks < 2; ks++) {
      const int j0 = ks * 2 + lhalf;
      const int ra = (wave & 1) * 32 + l31;
      bf16x8 af = *(const bf16x8*)&As2[ra * 32 + ((j0 ^ ((ra >> 1) & 3)) * 8)];
      #pragma unroll
      for (int cf = 0; cf < 5; cf++) {
        const int bn = (wave >> 1) * 160 + cf * 32 + l31;
        bf16x8 bv = *(const bf16x8*)&Bs2[bn * 32 + ((j0 ^ ((bn >> 1) & 3)) * 8)];
        acc[cf] = __builtin_amdgcn_mfma_f32_32x32x16_bf16(af, bv, acc[cf], 0, 0, 0);
      }
    }
    __syncthreads();
  }

  const int colb = (wave >> 1) * 160;
  const int rowb = m0 + (wave & 1) * 32 + 4 * lhalf;
  #pragma unroll
  for (int cf = 0; cf < 5; cf++) {
    const int col = colb + cf * 32 + l31;
    const float bv = (col < 87) ? bias[col] : (col < 93 ? bias2[col - 87] : 0.f);
    f32x16 v = acc[cf];
    #pragma unroll
    for (int r = 0; r < 16; r++) {
      const int row = rowb + (r & 3) + 8 * (r >> 2);
      if (row >= M) continue;
      float val = v[r] + bv;
      if (col < 87) out[(size_t)row * 87 + col] = val;
      else if (col < 93) out2[(size_t)row * 6 + (col - 87)] = val;
    }
  }
}

// ---------------------------------------------------------------------------
// gemm3_k: GEMM with FUSED A-GENERATION (r12-proven).
// NIN=2 MODE_EMB: node init. NIN=3 MODE_EBF16: edge MLP in CSR order
// (row p pulls eattr[eids[p]]; sequential e_csr writes).
// ---------------------------------------------------------------------------
template<int NIN, int MODE>
__global__ __launch_bounds__(256, 3)
void gemm3_k(const float* __restrict__ in0, const float* __restrict__ in1,
             const float* __restrict__ aw, const float* __restrict__ ab1,
             const bf16_t* __restrict__ Wt, const float* __restrict__ bias,
             void* outv, int M, const int* __restrict__ z,
             const float* __restrict__ emb)
{
  __shared__ bf16_t As2[64 * 32];
  __shared__ bf16_t Bs2[320 * 32];

  const int tid = threadIdx.x;
  const int wave = tid >> 6;
  const int lane = tid & 63;
  const int lhalf = lane >> 5;
  const int l31 = lane & 31;
  const int m0 = blockIdx.x * 64;

  const int lr = lane >> 2;
  const int lu = lane & 3;

  const int ar = wave * 16 + lr;
  const int au = lu ^ ((ar >> 1) & 3);
  int arow = m0 + ar; if (arow >= M) arow = M - 1;

  float a0, a1, a2 = 0.f;
  if constexpr (NIN == 2) {
    a0 = in0[arow]; a1 = in1[arow];
  } else {
    long erow = arow;
    if constexpr (MODE == MODE_EBF16) erow = z[arow];  // CSR position -> edge id
    a0 = in0[erow * 3 + 0];
    a1 = in0[erow * 3 + 1];
    a2 = in0[erow * 3 + 2];
  }

  const bf16_t* bsrc[5];
  #pragma unroll
  for (int c = 0; c < 5; c++) {
    int q = wave * 5 + c;
    int bn = q * 16 + lr;
    int bu = lu ^ ((bn >> 1) & 3);
    bsrc[c] = Wt + (size_t)bn * LDP + bu * 8;
  }

  f32x16 acc[5] = {};

  for (int k0 = 0; k0 < LDP; k0 += 32) {
    {
      const int cb = k0 + au * 8;
      bf16x8 v;
      #pragma unroll
      for (int j = 0; j < 8; j++) {
        const int cc = cb + j;
        float t = 0.f;
        if (cc < DD) {
          t = a0 * aw[cc] + a1 * aw[DD + cc];
          if constexpr (NIN == 3) t += a2 * aw[2 * DD + cc];
          t = fmaxf(t + ab1[cc], 0.f);
        }
        v[j] = (bf16_t)t;
      }
      *(bf16x8*)&As2[ar * 32 + lu * 8] = v;
    }
    #pragma unroll
    for (int c = 0; c < 5; c++)
      gload16(bsrc[c] + k0, Bs2 + (wave * 5 + c) * 512);
    __syncthreads();
    #pragma unroll
    for (int ks = 0; ks < 2; ks++) {
      const int j0 = ks * 2 + lhalf;
      const int ra = (wave & 1) * 32 + l31;
      bf16x8 af = *(const bf16x8*)&As2[ra * 32 + ((j0 ^ ((ra >> 1) & 3)) * 8)];
      #pragma unroll
      for (int cf = 0; cf < 5; cf++) {
        const int bn = (wave >> 1) * 160 + cf * 32 + l31;
        bf16x8 bv = *(const bf16x8*)&Bs2[bn * 32 + ((j0 ^ ((bn >> 1) & 3)) * 8)];
        acc[cf] = __builtin_amdgcn_mfma_f32_32x32x16_bf16(af, bv, acc[cf], 0, 0, 0);
      }
    }
    __syncthreads();
  }

  const int colb = (wave >> 1) * 160;
  const int rowb = m0 + (wave & 1) * 32 + 4 * lhalf;
  #pragma unroll
  for (int cf = 0; cf < 5; cf++) {
    const int col = colb + cf * 32 + l31;
    const float bv = (col < DD) ? bias[col] : 0.f;
    f32x16 v = acc[cf];
    #pragma unroll
    for (int r = 0; r < 16; r++) {
      const int row = rowb + (r & 3) + 8 * (r >> 2);
      if (row >= M) continue;
      float val = v[r] + bv;
      if constexpr (MODE == MODE_EBF16) {
        if (col < EST)
          ((bf16_t*)outv)[(size_t)row * EST + col] = (bf16_t)val;
      } else if constexpr (MODE == MODE_EPERM) {
        if (col < EST)
          ((bf16_t*)outv)[(size_t)z[row] * EST + col] = (bf16_t)val;
      } else {  // MODE_EMB
        float add = (col < DD) ? emb[(size_t)z[row] * DD + col] : 0.f;
        ((bf16_t*)outv)[(size_t)row * LDP + col] = (bf16_t)(val + add);
      }
    }
  }
}

// ---------------------------------------------------------------------------
// gemm_mlp_g: gather(+BN) FUSED into the per-layer MLP.
// Phase 0: g-tile computed directly into Ts (LDS) — 2560 tasks, 10/thread,
// identical math/coalescing to the old standalone gather_bn, bit-identical
// rounding (fp32 acc -> bf16 into Ts). GEMM1 reads A straight from Ts (no
// As2, no per-K-step A staging); after the K-loop's trailing barrier,
// epilogue-1 overwrites Ts with t; GEMM2 + BN-sums epilogue unchanged.
// Deletes the g buffer's 64MB write + 64MB read per layer and 1 dispatch.
// NOT in-place: src rows of R are read by other blocks -> ping-pong h<->G.
// W2 = W1t + 5*WSLOT. LDS 63.5KB -> 2 blocks/CU (same as before).
// ---------------------------------------------------------------------------
template<bool BN>
__global__ __launch_bounds__(256, 2)
void gemm_mlp_g(const bf16_t* __restrict__ R, const bf16_t* __restrict__ ecsr,
                const int* __restrict__ src_csr, const int* __restrict__ rowptr,
                const float* __restrict__ ab, const bf16_t* __restrict__ W1t,
                const float* __restrict__ b1, const float* __restrict__ b2,
                bf16_t* __restrict__ uout, int M, float* __restrict__ sums)
{
  __shared__ bf16_t Bs2[320 * 32];   // 20 KB (W1 then W2 panels)
  __shared__ bf16_t Ts[64 * TLD];    // 41 KB g-tile, then t-tile
  __shared__ float  red[2 * 320];

  const int tid = threadIdx.x;
  const int wave = tid >> 6;
  const int lane = tid & 63;
  const int lhalf = lane >> 5;
  const int l31 = lane & 31;
  const int m0 = blockIdx.x * 64;

  const int lr = lane >> 2;
  const int lu = lane & 3;

  // ---- phase 0: fused gather(+BN) into Ts ----
  for (int task = tid; task < 64 * 40; task += 256) {
    int lrow = task / 40;
    int cg = task - lrow * 40;
    int c = cg * 8;
    int row = m0 + lrow; if (row >= M) row = M - 1;  // dup work; masked at u-write
    bf16x8 o;
    if (c >= EST) {           // pad cols 304..319 -> exact zeros
      bf16x8 zz = {};
      o = zz;
    } else {
      float a_[8], b_[8];
      if constexpr (BN) {
        #pragma unroll
        for (int j = 0; j < 8; j++) {
          bool v = (c + j) < DD;
          a_[j] = v ? ab[c + j] : 0.f;
          b_[j] = v ? ab[LDP + c + j] : 0.f;
        }
      }
      int r0 = rowptr[row], r1 = rowptr[row + 1];
      bf16x8 hv = *(const bf16x8*)(R + (size_t)row * LDP + c);
      float acc[8];
      #pragma unroll
      for (int j = 0; j < 8; j++) {
        float x = (float)hv[j];
        if constexpr (BN) x = fmaxf(x * a_[j] + b_[j], 0.f);
        acc[j] = x;
      }
      if (r0 < r1) {
        int s = src_csr[r0];
        for (int r = r0; r < r1;) {
          bf16x8 a = *(const bf16x8*)(R + (size_t)s * LDP + c);
          bf16x8 ev = *(const bf16x8*)(ecsr + (size_t)r * EST + c);
          ++r;
          if (r < r1) s = src_csr[r];  // prefetch next src row id
          #pragma unroll
          for (int j = 0; j < 8; j++) {
            float x = (float)a[j];
            if constexpr (BN) x = fmaxf(x * a_[j] + b_[j], 0.f);
            acc[j] += fmaxf(x + (float)ev[j], 0.f);
          }
        }
      }
      #pragma unroll
      for (int j = 0; j < 8; j++) o[j] = (bf16_t)acc[j];
    }
    *(bf16x8*)&Ts[lrow * TLD + c] = o;
  }
  __syncthreads();   // Ts(g) published to all waves

  const bf16_t* bsrc[5];
  #pragma unroll
  for (int c = 0; c < 5; c++) {
    int q = wave * 5 + c;
    int bn = q * 16 + lr;
    int bu = lu ^ ((bn >> 1) & 3);
    bsrc[c] = W1t + (size_t)bn * LDP + bu * 8;
  }

  f32x16 acc[5] = {};
  const int colb = (wave >> 1) * 160;
  const int lrowb = (wave & 1) * 32 + 4 * lhalf;

  // ---- GEMM1: t = relu(g @ W1 + b1), A direct from Ts ----
  for (int k0 = 0; k0 < LDP; k0 += 32) {
    #pragma unroll
    for (int c = 0; c < 5; c++)
      gload16(bsrc[c] + k0, Bs2 + (wave * 5 + c) * 512);
    __syncthreads();
    #pragma unroll
    for (int ks = 0; ks < 2; ks++) {
      const int j0 = ks * 2 + lhalf;
      const int ra = (wave & 1) * 32 + l31;
      bf16x8 af = *(const bf16x8*)&Ts[ra * TLD + k0 + j0 * 8];
      #pragma unroll
      for (int cf = 0; cf < 5; cf++) {
        const int bn = (wave >> 1) * 160 + cf * 32 + l31;
        bf16x8 bv = *(const bf16x8*)&Bs2[bn * 32 + ((j0 ^ ((bn >> 1) & 3)) * 8)];
        acc[cf] = __builtin_amdgcn_mfma_f32_32x32x16_bf16(af, bv, acc[cf], 0, 0, 0);
      }
    }
    __syncthreads();   // also separates last Ts(g) read from t overwrite
  }

  // epilogue 1 -> Ts := t (relu + bf16 round; W1 pad cols zero -> t pad = 0)
  #pragma unroll
  for (int cf = 0; cf < 5; cf++) {
    const int col = colb + cf * 32 + l31;
    const float bv1 = (col < DD) ? b1[col] : 0.f;
    f32x16 v = acc[cf];
    #pragma unroll
    for (int r = 0; r < 16; r++) {
      const int lrow = lrowb + (r & 3) + 8 * (r >> 2);
      Ts[lrow * TLD + col] = (bf16_t)fmaxf(v[r] + bv1, 0.f);
    }
  }
  {
    f32x16 zz = {};
    #pragma unroll
    for (int cf = 0; cf < 5; cf++) acc[cf] = zz;
  }

  // ---- GEMM2: u = t @ W2 + b2  (first barrier below publishes Ts=t) ----
  for (int k0 = 0; k0 < LDP; k0 += 32) {
    #pragma unroll
    for (int c = 0; c < 5; c++)
      gload16(bsrc[c] + (size_t)5 * WSLOT + k0, Bs2 + (wave * 5 + c) * 512);
    __syncthreads();
    #pragma unroll
    for (int ks = 0; ks < 2; ks++) {
      const int j0 = ks * 2 + lhalf;
      const int ra = (wave & 1) * 32 + l31;
      bf16x8 af = *(const bf16x8*)&Ts[ra * TLD + k0 + j0 * 8];
      #pragma unroll
      for (int cf = 0; cf < 5; cf++) {
        const int bn = (wave >> 1) * 160 + cf * 32 + l31;
        bf16x8 bv = *(const bf16x8*)&Bs2[bn * 32 + ((j0 ^ ((bn >> 1) & 3)) * 8)];
        acc[cf] = __builtin_amdgcn_mfma_f32_32x32x16_bf16(af, bv, acc[cf], 0, 0, 0);
      }
    }
    __syncthreads();
  }

  // epilogue 2: bias2, bf16 u, BN sums (fp32 pre-rounding), block-combined atomics
  float s1[5], s2[5];
  #pragma unroll
  for (int i = 0; i < 5; i++) { s1[i] = 0.f; s2[i] = 0.f; }
  const int rowb = m0 + lrowb;
  #pragma unroll
  for (int cf = 0; cf < 5; cf++) {
    const int col = colb + cf * 32 + l31;
    const float bv2 = (col < DD) ? b2[col] : 0.f;
    f32x16 v = acc[cf];
    #pragma unroll
    for (int r = 0; r < 16; r++) {
      const int row = rowb + (r & 3) + 8 * (r >> 2);
      if (row >= M) continue;
      float val = v[r] + bv2;
      uout[(size_t)row * LDP + col] = (bf16_t)val;
      s1[cf] += val; s2[cf] += val * val;
    }
  }
  float t1[5], t2[5];
  #pragma unroll
  for (int cf = 0; cf < 5; cf++) {
    t1[cf] = s1[cf] + __shfl_down(s1[cf], 32);
    t2[cf] = s2[cf] + __shfl_down(s2[cf], 32);
  }
  if ((wave & 1) == 0 && lhalf == 0) {
    #pragma unroll
    for (int cf = 0; cf < 5; cf++) {
      const int col = colb + cf * 32 + l31;
      red[col] = t1[cf];
      red[320 + col] = t2[cf];
    }
  }
  __syncthreads();
  if ((wave & 1) == 1 && lhalf == 0) {
    #pragma unroll
    for (int cf = 0; cf < 5; cf++) {
      const int col = colb + cf * 32 + l31;
      if (col < DD) {
        atomicAdd(&sums[col], t1[cf] + red[col]);
        atomicAdd(&sums[LDP + col], t2[cf] + red[320 + col]);
      }
    }
  }
}

// ---------------------------------------------------------------------------
// old gemm_k: fallback (scatter) path only
// ---------------------------------------------------------------------------
template<bool ABF16, int MODE>
__global__ __launch_bounds__(256, 2)
void gemm_k(const void* Av, const bf16_t* __restrict__ Wt,
            const float* __restrict__ bias, void* outv, int M,
            const int* __restrict__ z, const float* __restrict__ emb,
            float* __restrict__ out2, const float* __restrict__ bias2)
{
  __shared__ bf16_t As[128 * 40];
  __shared__ bf16_t Bs[320 * 40];
  const int tid = threadIdx.x;
  const int wave = tid >> 6;
  const int lane = tid & 63;
  const int lhalf = lane >> 5;
  const int l31 = lane & 31;
  const int m0 = blockIdx.x * 128;

  f32x16 acc[2][5] = {};

  for (int k0 = 0; k0 < LDP; k0 += 32) {
    #pragma unroll
    for (int i = 0; i < 5; i++) {
      int idx = tid + i * 256;
      int n = idx >> 2, cv = idx & 3;
      *(bf16x8*)&Bs[n * 40 + cv * 8] =
          *(const bf16x8*)(Wt + (size_t)n * LDP + k0 + cv * 8);
    }
    if constexpr (ABF16) {
      const bf16_t* A = (const bf16_t*)Av;
      #pragma unroll
      for (int i = 0; i < 2; i++) {
        int r = (tid >> 2) + i * 64;
        int cv = tid & 3;
        int row = m0 + r;
        bf16x8 v = {};
        if (row < M) v = *(const bf16x8*)(A + (size_t)row * LDP + k0 + cv * 8);
        *(bf16x8*)&As[r * 40 + cv * 8] = v;
      }
    } else {
      const float* A = (const float*)Av;
      #pragma unroll
      for (int i = 0; i < 4; i++) {
        int r = (tid >> 3) + i * 32;
        int cv = tid & 7;
        int row = m0 + r;
        float fx = 0.f, fy = 0.f, fz2 = 0.f, fw = 0.f;
        if (row < M) {
          const float4 f = *(const float4*)(A + (size_t)row * LDP + k0 + cv * 4);
          fx = f.x; fy = f.y; fz2 = f.z; fw = f.w;
        }
        bf16x4 v;
        v.x = (bf16_t)fx; v.y = (bf16_t)fy; v.z = (bf16_t)fz2; v.w = (bf16_t)fw;
        *(bf16x4*)&As[r * 40 + cv * 4] = v;
      }
    }
    __syncthreads();
    #pragma unroll
    for (int ks = 0; ks < 2; ks++) {
      const int kk = ks * 16 + lhalf * 8;
      bf16x8 af0 = *(const bf16x8*)&As[((wave & 1) * 64 + 0  + l31) * 40 + kk];
      bf16x8 af1 = *(const bf16x8*)&As[((wave & 1) * 64 + 32 + l31) * 40 + kk];
      #pragma unroll
      for (int cf = 0; cf < 5; cf++) {
        bf16x8 bv = *(const bf16x8*)&Bs[((wave >> 1) * 160 + cf * 32 + l31) * 40 + kk];
        acc[0][cf] = __builtin_amdgcn_mfma_f32_32x32x16_bf16(af0, bv, acc[0][cf], 0, 0, 0);
        acc[1][cf] = __builtin_amdgcn_mfma_f32_32x32x16_bf16(af1, bv, acc[1][cf], 0, 0, 0);
      }
    }
    __syncthreads();
  }

  const int colb = (wave >> 1) * 160;
  float s1[5], s2[5];
  #pragma unroll
  for (int i = 0; i < 5; i++) { s1[i] = 0.f; s2[i] = 0.f; }

  #pragma unroll
  for (int rf = 0; rf < 2; rf++) {
    const int rowb = m0 + (wave & 1) * 64 + rf * 32 + 4 * lhalf;
    #pragma unroll
    for (int cf = 0; cf < 5; cf++) {
      const int col = colb + cf * 32 + l31;
      float bv;
      if constexpr (MODE == MODE_HEAD) {
        bv = (col < 87) ? bias[col] : (col < 93 ? bias2[col - 87] : 0.f);
      } else {
        bv = (col < DD) ? bias[col] : 0.f;
      }
      f32x16 v = acc[rf][cf];
      #pragma unroll
      for (int r = 0; r < 16; r++) {
        const int row = rowb + (r & 3) + 8 * (r >> 2);
        if (row >= M) continue;
        float val = v[r] + bv;
        if constexpr (MODE == MODE_F32S) {
          ((float*)outv)[(size_t)row * LDP + col] = val;
          s1[cf] += val; s2[cf] += val * val;
        } else if constexpr (MODE == MODE_BF16_RELU) {
          ((bf16_t*)outv)[(size_t)row * LDP + col] = (bf16_t)fmaxf(val, 0.f);
        } else if constexpr (MODE == MODE_BF16) {
          ((bf16_t*)outv)[(size_t)row * LDP + col] = (bf16_t)val;
        } else if constexpr (MODE == MODE_EMB) {
          float add = (col < DD) ? emb[(size_t)z[row] * DD + col] : 0.f;
          ((bf16_t*)outv)[(size_t)row * LDP + col] = (bf16_t)(val + add);
        } else {  // MODE_HEAD
          if (col < 87) ((float*)outv)[(size_t)row * 87 + col] = val;
          else if (col < 93) out2[(size_t)row * 6 + (col - 87)] = val;
        }
      }
    }
  }

  if constexpr (MODE == MODE_F32S) {
    #pragma unroll
    for (int cf = 0; cf < 5; cf++) {
      const int col = colb + cf * 32 + l31;
      float o1 = __shfl_down(s1[cf], 32);
      float o2 = __shfl_down(s2[cf], 32);
      if (lhalf == 0 && col < DD) {
        atomicAdd(&out2[col], s1[cf] + o1);
        atomicAdd(&out2[LDP + col], s2[cf] + o2);
      }
    }
  }
}

__global__ void stage1_node(const float* __restrict__ ch, const float* __restrict__ fc,
                            const float* __restrict__ w1, const float* __restrict__ b1,
                            bf16_t* __restrict__ t, int n) {
  int idx = blockIdx.x * 256 + threadIdx.x;
  if (idx >= n * LDP) return;
  int i = idx / LDP;
  int c = idx - i * LDP;
  float v = 0.f;
  if (c < DD) v = fmaxf(ch[i] * w1[c] + fc[i] * w1[DD + c] + b1[c], 0.f);
  t[idx] = (bf16_t)v;
}

__global__ void stage1_edge(const float* __restrict__ ea,
                            const float* __restrict__ w1, const float* __restrict__ b1,
                            bf16_t* __restrict__ t, int n) {
  int idx = blockIdx.x * 256 + threadIdx.x;
  if (idx >= n * LDP) return;
  int i = idx / LDP;
  int c = idx - i * LDP;
  float v = 0.f;
  if (c < DD) {
    float a0 = ea[(long)i * 3 + 0], a1 = ea[(long)i * 3 + 1], a2 = ea[(long)i * 3 + 2];
    v = fmaxf(a0 * w1[c] + a1 * w1[DD + c] + a2 * w1[2 * DD + c] + b1[c], 0.f);
  }
  t[idx] = (bf16_t)v;
}

// ---------------- CSR build (once per launch; lives in d_out scratch) ----------------
__global__ void csr_zero(int* __restrict__ p, int n) {
  int i = blockIdx.x * 256 + threadIdx.x;
  if (i < n) p[i] = 0;
}
__global__ void csr_hist(const int* __restrict__ dst, int* __restrict__ cnt, int E) {
  int e = blockIdx.x * 256 + threadIdx.x;
  if (e < E) atomicAdd(&cnt[dst[e]], 1);
}
__global__ void csr_part(const int* __restrict__ cnt, int* __restrict__ psum, int n) {
  __shared__ int wsum[4];
  int b = blockIdx.x, t = threadIdx.x;
  int i = b * 256 + t;
  int v = (i < n) ? cnt[i] : 0;
  #pragma unroll
  for (int o = 32; o > 0; o >>= 1) v += __shfl_down(v, o);
  if ((t & 63) == 0) wsum[t >> 6] = v;
  __syncthreads();
  if (t == 0) psum[b] = wsum[0] + wsum[1] + wsum[2] + wsum[3];
}
__global__ void csr_scan_small(int* __restrict__ psum, int nb) {
  if (threadIdx.x == 0) {
    int acc = 0;
    for (int i = 0; i < nb; i++) { int v = psum[i]; psum[i] = acc; acc += v; }
    psum[nb] = acc;
  }
}
__global__ void csr_scan_final(const int* __restrict__ cnt, const int* __restrict__ psum,
                               int* __restrict__ rowptr, int* __restrict__ cursor, int n) {
  __shared__ int sh[256];
  int b = blockIdx.x, t = threadIdx.x;
  int i = b * 256 + t;
  sh[t] = (i < n) ? cnt[i] : 0;
  __syncthreads();
  int s = psum[b];
  for (int j = 0; j < t; j++) s += sh[j];
  if (i <= n) {
    rowptr[i] = s;
    if (i < n) cursor[i] = s;
  }
}
__global__ void csr_fill(const int* __restrict__ dst, int* __restrict__ cursor,
                         int* __restrict__ eids, int E) {
  int e = blockIdx.x * 256 + threadIdx.x;
  if (e < E) { int p = atomicAdd(&cursor[dst[e]], 1); eids[p] = e; }
}
__global__ void csr_pos_src(const int* __restrict__ eids, const int* __restrict__ src,
                            int* __restrict__ pos, int* __restrict__ src_csr, int E) {
  int p = blockIdx.x * 256 + threadIdx.x;
  if (p < E) { int e = eids[p]; pos[e] = p; src_csr[p] = src[e]; }
}

// ---------------- fallback-path kernels (chunked scatter; unchanged) ----------------
__global__ void init_hh(const bf16_t* __restrict__ h, float* __restrict__ hh, int total) {
  int idx = blockIdx.x * 256 + threadIdx.x;
  if (idx >= total) return;
  hh[idx] = (float)h[idx];
}

__global__ void scatter_k(const bf16_t* __restrict__ h, const bf16_t* __restrict__ e,
                          const int* __restrict__ src, const int* __restrict__ dst,
                          float* __restrict__ hh, int E) {
  int idx = blockIdx.x * 256 + threadIdx.x;
  if (idx >= E * 75) return;
  int ed = idx / 75;
  int q = idx - ed * 75;
  int s = src[ed], d = dst[ed];
  const bf16x4 hv = *(const bf16x4*)(h + (size_t)s * LDP + q * 4);
  const bf16x4 ev = *(const bf16x4*)(e + (size_t)ed * LDP + q * 4);
  float* o = hh + (size_t)d * LDP + q * 4;
  atomicAdd(o + 0, fmaxf((float)hv.x + (float)ev.x, 0.f));
  atomicAdd(o + 1, fmaxf((float)hv.y + (float)ev.y, 0.f));
  atomicAdd(o + 2, fmaxf((float)hv.z + (float)ev.z, 0.f));
  atomicAdd(o + 3, fmaxf((float)hv.w + (float)ev.w, 0.f));
}

__global__ void zero_sums(float* __restrict__ sums) { sums[threadIdx.x] = 0.f; }

// reads per-column sums -> writes ab, then RE-ZEROS sums for the next layer
__global__ void bn_final(float* __restrict__ sums, const float* __restrict__ gamma,
                         const float* __restrict__ beta, float* __restrict__ ab, int n) {
  int c = threadIdx.x;
  if (c >= LDP) return;
  float s1 = sums[c], s2 = sums[LDP + c];
  sums[c] = 0.f;
  sums[LDP + c] = 0.f;
  if (c >= DD) return;
  float inv_n = 1.f / (float)n;
  float mean = s1 * inv_n;
  float var = s2 * inv_n - mean * mean;  // biased var (torch/jnp)
  float a = gamma[c] * rsqrtf(fmaxf(var, 0.f) + 1e-5f);
  ab[c] = a;
  ab[LDP + c] = beta[c] - mean * a;
}

__global__ void bn_apply(float* u, const float* __restrict__ ab,
                         bf16_t* __restrict__ h, int total) {
  int idx = blockIdx.x * 256 + threadIdx.x;
  if (idx >= total) return;
  int c = idx % LDP;
  float v = 0.f;
  if (c < DD) v = fmaxf(u[idx] * ab[c] + ab[LDP + c], 0.f);
  h[idx] = (bf16_t)v;
  u[idx] = v;
}

extern "C" void kernel_launch(void* const* d_in, const int* in_sizes, int n_in,
                              void* d_out, int out_size, void* d_ws, size_t ws_size,
                              hipStream_t stream) {
  const int*   z        = (const int*)d_in[0];
  const float* chir     = (const float*)d_in[1];
  const float* fchg     = (const float*)d_in[2];
  const int*   eidx     = (const int*)d_in[3];
  const float* eattr    = (const float*)d_in[4];
  const float* atom_emb = (const float*)d_in[5];
  const float* nap_w1   = (const float*)d_in[6];
  const float* nap_b1   = (const float*)d_in[7];
  const float* nap_w2   = (const float*)d_in[8];
  const float* nap_b2   = (const float*)d_in[9];
  const float* ee_w1    = (const float*)d_in[10];
  const float* ee_b1    = (const float*)d_in[11];
  const float* ee_w2    = (const float*)d_in[12];
  const float* ee_b2    = (const float*)d_in[13];
  const float* gnn_w1   = (const float*)d_in[14];
  const float* gnn_b1   = (const float*)d_in[15];
  const float* gnn_w2   = (const float*)d_in[16];
  const float* gnn_b2   = (const float*)d_in[17];
  const float* bn_gamma = (const float*)d_in[18];
  const float* bn_beta  = (const float*)d_in[19];
  const float* ah_w     = (const float*)d_in[20];
  const float* ah_b     = (const float*)d_in[21];
  const float* ch_w     = (const float*)d_in[22];
  const float* ch_b     = (const float*)d_in[23];

  const int N = in_sizes[0];
  const int E = in_sizes[3] / 2;
  const int* src = eidx;
  const int* dst = eidx + E;

  char* ws = (char*)d_ws;
  size_t off = 0;
  auto take = [&](size_t bytes) -> void* {
    void* p = ws + off;
    off = (off + bytes + 255) & ~(size_t)255;
    return p;
  };
  auto alignup = [](size_t x) { return (x + 255) & ~(size_t)255; };

  bf16_t* wt12 = (bf16_t*)take((size_t)12 * WSLOT * 2);
  bf16_t* wtH  = (bf16_t*)take((size_t)WSLOT * 2);
  float*  sums = (float*)take((size_t)2 * LDP * 4);
  float*  ab   = (float*)take((size_t)2 * LDP * 4);
  bf16_t* h    = (bf16_t*)take((size_t)N * LDP * 2);   // bf16 buffer (ping)
  const size_t head_end = off;

  // fused tier: proven-fit 252.27MB layout: h + G + e_csr
  const size_t u16_b = (size_t)N * LDP * 2;
  const size_t e_b   = (size_t)E * EST * 2 + 256;
  const size_t need1 = head_end + alignup(u16_b) + alignup(e_b);
  int tier = (ws_size >= need1) ? 1 : 0;

  bf16_t* G      = nullptr;   // bf16 buffer (pong)
  bf16_t* e_csr  = nullptr;
  float*  hh     = nullptr;   // fallback fp32 aggregate
  bf16_t* echunk = nullptr;
  int EC = 0;
  if (tier) {
    G     = (bf16_t*)take(u16_b);
    e_csr = (bf16_t*)take(e_b);
  } else {
    hh = (float*)take((size_t)N * LDP * 4);
    const size_t base_end = off;
    if (ws_size < base_end) return;
    size_t slack = (ws_size > base_end + 256) ? (ws_size - base_end - 256) : 0;
    size_t ec_ws  = slack / (LDP * 2);
    size_t ec_out = ((size_t)out_size * 4) / (LDP * 2);
    size_t ec = ec_ws < ec_out ? ec_ws : ec_out;
    if (ec > (size_t)E) ec = E;
    ec &= ~(size_t)127;
    if (ec < 128) return;
    EC = (int)ec;
    echunk = (bf16_t*)take((size_t)EC * LDP * 2);
  }
  (void)n_in;

  Src12 s;
  s.p[0] = nap_w2; s.p[1] = ee_w2;
  for (int l = 0; l < 5; l++) {
    s.p[2 + l] = gnn_w1 + (size_t)l * DD * DD;
    s.p[7 + l] = gnn_w2 + (size_t)l * DD * DD;
  }
  prep_wt_all<<<dim3((WSLOT + 255) / 256, 12), 256, 0, stream>>>(s, wt12);
  prep_wt_head<<<(WSLOT + 255) / 256, 256, 0, stream>>>(ah_w, ch_w, wtH);

  const int gN = (N + 127) / 128;     // old-gemm grid (fallback)
  const int g2N = (N + 63) / 64;      // 64-row-tile grid

  if (tier) {
    // ---- CSR build in d_out scratch (legal until head GEMM) ----
    int* rowptr  = (int*)d_out;          // N+1
    int* src_csr = rowptr + (N + 1);     // E
    int* eids    = src_csr + E;          // E  (read by CSR-order edge GEMM)
    int* pos     = eids + E;             // E
    int* cnt     = pos + E;              // N
    int* cursor  = cnt + N;              // N
    int* psum    = cursor + N;           // NBLK+1
    const int NBLK = (N + 255) / 256;
    csr_zero<<<NBLK, 256, 0, stream>>>(cnt, N);
    csr_hist<<<(E + 255) / 256, 256, 0, stream>>>(dst, cnt, E);
    csr_part<<<NBLK, 256, 0, stream>>>(cnt, psum, N);
    csr_scan_small<<<1, 64, 0, stream>>>(psum, NBLK);
    csr_scan_final<<<(N + 256) / 256, 256, 0, stream>>>(cnt, psum, rowptr, cursor, N);
    csr_fill<<<(E + 255) / 256, 256, 0, stream>>>(dst, cursor, eids, E);
    csr_pos_src<<<(E + 255) / 256, 256, 0, stream>>>(eids, src, pos, src_csr, E);

    // edge features: ONE fused launch in CSR ORDER (r12-proven)
    gemm3_k<3, MODE_EBF16><<<(E + 63) / 64, 256, 0, stream>>>(
        eattr, nullptr, ee_w1, ee_b1, wt12 + (size_t)1 * WSLOT, ee_b2,
        e_csr, E, eids, nullptr);

    // node init fused: h = atom_emb[z] + relu(na@nap_w1+b1)@nap_w2+b2
    gemm3_k<2, MODE_EMB><<<g2N, 256, 0, stream>>>(
        chir, fchg, nap_w1, nap_b1, wt12 + (size_t)0 * WSLOT, nap_b2,
        h, N, z, atom_emb);

    // layers: fused gather(+BN)+MLP, ping-pong h <-> G (NOT in-place: other
    // blocks read src rows of the input buffer)
    zero_sums<<<1, 2 * LDP, 0, stream>>>(sums);   // once; bn_final re-zeros
    for (int l = 0; l < 5; l++) {
      const bf16_t* gin = (l & 1) ? G : h;
      bf16_t* gout = (l & 1) ? h : G;
      if (l == 0)
        gemm_mlp_g<false><<<g2N, 256, 0, stream>>>(
            gin, e_csr, src_csr, rowptr, nullptr, wt12 + (size_t)2 * WSLOT,
            gnn_b1, gnn_b2, gout, N, sums);
      else
        gemm_mlp_g<true><<<g2N, 256, 0, stream>>>(
            gin, e_csr, src_csr, rowptr, ab, wt12 + (size_t)(2 + l) * WSLOT,
            gnn_b1 + (size_t)l * DD, gnn_b2 + (size_t)l * DD, gout, N, sums);
      bn_final<<<1, LDP, 0, stream>>>(sums, bn_gamma + (size_t)l * DD,
                                      bn_beta + (size_t)l * DD, ab, N);
    }
    // u4 lives in G (l=4: gin=h, gout=G) -> head with fused relu(BN(.)) A-gen
    gemm_hd<<<g2N, 256, 0, stream>>>(
        G, ab, wtH, ah_b, (float*)d_out, N,
        (float*)d_out + (size_t)N * 87, ch_b);
  } else {
    // -------- fallback: original chunked scatter path (unchanged) --------
    stage1_node<<<((long)N * LDP + 255) / 256, 256, 0, stream>>>(chir, fchg, nap_w1, nap_b1, h, N);
    gemm_k<true, MODE_EMB><<<gN, 256, 0, stream>>>(
        h, wt12 + (size_t)0 * WSLOT, nap_b2, h, N, z, atom_emb, nullptr, nullptr);

    for (int l = 0; l < 5; l++) {
      if (l == 0)
        init_hh<<<((long)N * LDP + 255) / 256, 256, 0, stream>>>(h, hh, N * LDP);
      bf16_t* estage = (bf16_t*)d_out;  // legal scratch until final head GEMM
      for (int c0 = 0; c0 < E; c0 += EC) {
        int curn = (E - c0 < EC) ? (E - c0) : EC;
        stage1_edge<<<((long)curn * LDP + 255) / 256, 256, 0, stream>>>(
            eattr + (size_t)c0 * 3, ee_w1, ee_b1, estage, curn);
        gemm_k<true, MODE_BF16><<<(curn + 127) / 128, 256, 0, stream>>>(
            estage, wt12 + (size_t)1 * WSLOT, ee_b2, echunk, curn,
            nullptr, nullptr, nullptr, nullptr);
        scatter_k<<<((long)curn * 75 + 255) / 256, 256, 0, stream>>>(
            h, echunk, src + c0, dst + c0, hh, curn);
      }
      gemm_k<false, MODE_BF16_RELU><<<gN, 256, 0, stream>>>(
          hh, wt12 + (size_t)(2 + l) * WSLOT, gnn_b1 + (size_t)l * DD, h, N,
          nullptr, nullptr, nullptr, nullptr);
      zero_sums<<<1, 2 * LDP, 0, stream>>>(sums);
      gemm_k<true, MODE_F32S><<<gN, 256, 0, stream>>>(
          h, wt12 + (size_t)(7 + l) * WSLOT, gnn_b2 + (size_t)l * DD, hh, N,
          nullptr, nullptr, sums, nullptr);
      bn_final<<<1, LDP, 0, stream>>>(sums, bn_gamma + (size_t)l * DD, bn_beta + (size_t)l * DD, ab, N);
      bn_apply<<<((long)N * LDP + 255) / 256, 256, 0, stream>>>(hh, ab, h, N * LDP);
    }

    gemm_k<true, MODE_HEAD><<<gN, 256, 0, stream>>>(
        h, wtH, ah_b, d_out, N, nullptr, nullptr, (float*)d_out + (size_t)N * 87, ch_b);
  }
}

// Round 15
// 1667.967 us; speedup vs baseline: 1.0343x; 1.0343x over previous
//
#include <hip/hip_runtime.h>

typedef __bf16 bf16_t;
typedef __bf16 bf16x4 __attribute__((ext_vector_type(4)));
typedef __bf16 bf16x8 __attribute__((ext_vector_type(8)));
typedef float f32x16 __attribute__((ext_vector_type(16)));

#define DD 300
#define LDP 320
#define EST 304   // packed stride for persistent CSR-ordered edge features
#define TLD 328   // padded LDS stride for the fused t-tile
#define WSLOT (LDP * LDP)

struct Src12 { const float* p[12]; };

// async global->LDS, 16B per lane (wave-uniform LDS base + lane*16)
__device__ __forceinline__ void gload16(const bf16_t* g, bf16_t* l) {
  __builtin_amdgcn_global_load_lds(
      (const __attribute__((address_space(1))) void*)g,
      (__attribute__((address_space(3))) void*)l, 16, 0, 0);
}

// wt[m][n*LDP + k] = W_m[k*DD + n], zero-padded to 320x320 (n-major, k-contig)
__global__ void prep_wt_all(Src12 s, bf16_t* __restrict__ wt) {
  int m = blockIdx.y;
  int idx = blockIdx.x * 256 + threadIdx.x;
  if (idx >= WSLOT) return;
  int n = idx / LDP, k = idx - n * LDP;
  float v = 0.f;
  if (n < DD && k < DD) v = s.p[m][(long)k * DD + n];
  wt[(size_t)m * WSLOT + idx] = (bf16_t)v;
}

__global__ void prep_wt_head(const float* __restrict__ ah_w, const float* __restrict__ ch_w,
                             bf16_t* __restrict__ wt) {
  int idx = blockIdx.x * 256 + threadIdx.x;
  if (idx >= WSLOT) return;
  int n = idx / LDP, k = idx - n * LDP;
  float v = 0.f;
  if (k < DD) {
    if (n < 87) v = ah_w[(long)k * 87 + n];
    else if (n < 93) v = ch_w[(long)k * 6 + (n - 87)];
  }
  wt[idx] = (bf16_t)v;
}

enum { MODE_F32S = 0, MODE_BF16_RELU = 1, MODE_BF16 = 2, MODE_EMB = 3, MODE_HEAD = 4,
       MODE_BF16S = 5, MODE_EPERM = 6, MODE_EBF16 = 7 };

// ---------------------------------------------------------------------------
// gemm2_k: single-buffered 64x320 GEMM — retained for fallback use.
// ---------------------------------------------------------------------------
template<int MODE>
__global__ __launch_bounds__(256, 3)
void gemm2_k(const bf16_t* Av, const bf16_t* __restrict__ Wt,
             const float* __restrict__ bias, void* outv, int M,
             const int* __restrict__ z, const float* __restrict__ emb,
             float* __restrict__ out2, const float* __restrict__ bias2)
{
  __shared__ bf16_t As2[64 * 32];
  __shared__ bf16_t Bs2[320 * 32];
  __shared__ float  red[2 * 320];

  const int tid = threadIdx.x;
  const int wave = tid >> 6;
  const int lane = tid & 63;
  const int lhalf = lane >> 5;
  const int l31 = lane & 31;
  const int m0 = blockIdx.x * 64;

  const int lr = lane >> 2;
  const int lu = lane & 3;

  const int ar = wave * 16 + lr;
  const int au = lu ^ ((ar >> 1) & 3);
  int arow = m0 + ar; if (arow >= M) arow = M - 1;
  const bf16_t* asrc = Av + (size_t)arow * LDP + au * 8;

  const bf16_t* bsrc[5];
  #pragma unroll
  for (int c = 0; c < 5; c++) {
    int q = wave * 5 + c;
    int bn = q * 16 + lr;
    int bu = lu ^ ((bn >> 1) & 3);
    bsrc[c] = Wt + (size_t)bn * LDP + bu * 8;
  }

  f32x16 acc[5] = {};

  for (int k0 = 0; k0 < LDP; k0 += 32) {
    gload16(asrc + k0, As2 + wave * 512);
    #pragma unroll
    for (int c = 0; c < 5; c++)
      gload16(bsrc[c] + k0, Bs2 + (wave * 5 + c) * 512);
    __syncthreads();
    #pragma unroll
    for (int ks = 0; ks < 2; ks++) {
      const int j0 = ks * 2 + lhalf;
      const int ra = (wave & 1) * 32 + l31;
      bf16x8 af = *(const bf16x8*)&As2[ra * 32 + ((j0 ^ ((ra >> 1) & 3)) * 8)];
      #pragma unroll
      for (int cf = 0; cf < 5; cf++) {
        const int bn = (wave >> 1) * 160 + cf * 32 + l31;
        bf16x8 bv = *(const bf16x8*)&Bs2[bn * 32 + ((j0 ^ ((bn >> 1) & 3)) * 8)];
        acc[cf] = __builtin_amdgcn_mfma_f32_32x32x16_bf16(af, bv, acc[cf], 0, 0, 0);
      }
    }
    __syncthreads();
  }

  const int colb = (wave >> 1) * 160;
  float s1[5], s2[5];
  #pragma unroll
  for (int i = 0; i < 5; i++) { s1[i] = 0.f; s2[i] = 0.f; }

  const int rowb = m0 + (wave & 1) * 32 + 4 * lhalf;
  #pragma unroll
  for (int cf = 0; cf < 5; cf++) {
    const int col = colb + cf * 32 + l31;
    float bv;
    if constexpr (MODE == MODE_HEAD) {
      bv = (col < 87) ? bias[col] : (col < 93 ? bias2[col - 87] : 0.f);
    } else {
      bv = (col < DD) ? bias[col] : 0.f;
    }
    f32x16 v = acc[cf];
    #pragma unroll
    for (int r = 0; r < 16; r++) {
      const int row = rowb + (r & 3) + 8 * (r >> 2);
      if (row >= M) continue;
      float val = v[r] + bv;
      if constexpr (MODE == MODE_F32S) {
        ((float*)outv)[(size_t)row * LDP + col] = val;
        s1[cf] += val; s2[cf] += val * val;
      } else if constexpr (MODE == MODE_BF16S) {
        ((bf16_t*)outv)[(size_t)row * LDP + col] = (bf16_t)val;
        s1[cf] += val; s2[cf] += val * val;
      } else if constexpr (MODE == MODE_BF16_RELU) {
        ((bf16_t*)outv)[(size_t)row * LDP + col] = (bf16_t)fmaxf(val, 0.f);
      } else if constexpr (MODE == MODE_BF16) {
        ((bf16_t*)outv)[(size_t)row * LDP + col] = (bf16_t)val;
      } else if constexpr (MODE == MODE_EPERM) {
        if (col < EST)
          ((bf16_t*)outv)[(size_t)z[row] * EST + col] = (bf16_t)val;
      } else if constexpr (MODE == MODE_EMB) {
        float add = (col < DD) ? emb[(size_t)z[row] * DD + col] : 0.f;
        ((bf16_t*)outv)[(size_t)row * LDP + col] = (bf16_t)(val + add);
      } else {  // MODE_HEAD
        if (col < 87) ((float*)outv)[(size_t)row * 87 + col] = val;
        else if (col < 93) out2[(size_t)row * 6 + (col - 87)] = val;
      }
    }
  }

  if constexpr (MODE == MODE_F32S || MODE == MODE_BF16S) {
    float t1[5], t2[5];
    #pragma unroll
    for (int cf = 0; cf < 5; cf++) {
      t1[cf] = s1[cf] + __shfl_down(s1[cf], 32);
      t2[cf] = s2[cf] + __shfl_down(s2[cf], 32);
    }
    if ((wave & 1) == 0 && lhalf == 0) {
      #pragma unroll
      for (int cf = 0; cf < 5; cf++) {
        const int col = colb + cf * 32 + l31;
        red[col] = t1[cf];
        red[320 + col] = t2[cf];
      }
    }
    __syncthreads();
    if ((wave & 1) == 1 && lhalf == 0) {
      #pragma unroll
      for (int cf = 0; cf < 5; cf++) {
        const int col = colb + cf * 32 + l31;
        if (col < DD) {
          atomicAdd(&out2[col], t1[cf] + red[col]);
          atomicAdd(&out2[LDP + col], t2[cf] + red[320 + col]);
        }
      }
    }
  }
}

// ---------------------------------------------------------------------------
// gemm_hd2: HEAD GEMM, 128 rows x 96 cols per block (only 93 output cols are
// real — the 320-col head wasted 71% of MFMA + B-staging on padding).
// 4 waves x 32 rows, 3 col-fragments; fused relu(BN(u)) A-generation
// (bit-identical to bn_apply2b rounding); same swizzle conventions.
// Both __syncthreads are reached unconditionally by all 256 threads
// (q<6 guards only the gload16 issuance). LDS 14.3KB -> high occupancy.
// ---------------------------------------------------------------------------
__global__ __launch_bounds__(256, 4)
void gemm_hd2(const bf16_t* __restrict__ U, const float* __restrict__ ab,
              const bf16_t* __restrict__ Wt, const float* __restrict__ bias,
              float* __restrict__ out, int M, float* __restrict__ out2,
              const float* __restrict__ bias2)
{
  __shared__ bf16_t As2[128 * 32];   // 8 KB
  __shared__ bf16_t Bs2[96 * 32];    // 6 KB

  const int tid = threadIdx.x;
  const int wave = tid >> 6;
  const int lane = tid & 63;
  const int lhalf = lane >> 5;
  const int l31 = lane & 31;
  const int m0 = blockIdx.x * 128;

  const int lr = lane >> 2;
  const int lu = lane & 3;

  // B staging: 6 wave-calls (96 rows); waves 0..2 take 2 each
  const int q0 = wave * 2, q1 = wave * 2 + 1;
  const bf16_t *bs0 = nullptr, *bs1 = nullptr;
  if (q0 < 6) { int bn = q0 * 16 + lr; int bu = lu ^ ((bn >> 1) & 3); bs0 = Wt + (size_t)bn * LDP + bu * 8; }
  if (q1 < 6) { int bn = q1 * 16 + lr; int bu = lu ^ ((bn >> 1) & 3); bs1 = Wt + (size_t)bn * LDP + bu * 8; }

  f32x16 acc[3] = {};

  for (int k0 = 0; k0 < LDP; k0 += 32) {
    // A-gen: 128 rows x 4 units; 512 cell-writes, 2 per thread
    #pragma unroll
    for (int t2 = 0; t2 < 2; t2++) {
      const int idx = tid + t2 * 256;
      const int arr = idx >> 2;          // 0..127
      const int ul  = idx & 3;           // cell unit
      const int au  = ul ^ ((arr >> 1) & 3);
      int arow = m0 + arr; if (arow >= M) arow = M - 1;
      const int cb = k0 + au * 8;
      bf16x8 uv = *(const bf16x8*)(U + (size_t)arow * LDP + cb);
      bf16x8 v;
      #pragma unroll
      for (int j = 0; j < 8; j++) {
        const int cc = cb + j;
        float x = 0.f;
        if (cc < DD) x = fmaxf((float)uv[j] * ab[cc] + ab[LDP + cc], 0.f);
        v[j] = (bf16_t)x;
      }
      *(bf16x8*)&As2[arr * 32 + ul * 8] = v;
    }
    if (q0 < 6) gload16(bs0 + k0, Bs2 + q0 * 512);
    if (q1 < 6) gload16(bs1 + k0, Bs2 + q1 * 512);
    __syncthreads();
    #pragma unroll
    for (int ks = 0; ks < 2; ks++) {
      const int j0 = ks * 2 + lhalf;
      const int ra = wave * 32 + l31;
      bf16x8 af = *(const bf16x8*)&As2[ra * 32 + ((j0 ^ ((ra >> 1) & 3)) * 8)];
      #pragma unroll
      for (int cf = 0; cf < 3; cf++) {
        const int bn = cf * 32 + l31;
        bf16x8 bv = *(const bf16x8*)&Bs2[bn * 32 + ((j0 ^ ((bn >> 1) & 3)) * 8)];
        acc[cf] = __builtin_amdgcn_mfma_f32_32x32x16_bf16(af, bv, acc[cf], 0, 0, 0);
      }
    }
    __syncthreads();
  }

  const int rowb = m0 + wave * 32 + 4 * lhalf;
  #pragma unroll
  for (int cf = 0; cf < 3; cf++) {
    const int col = cf * 32 + l31;
    const float bv = (col < 87) ? bias[col] : (col < 93 ? bias2[col - 87] : 0.f);
    f32x16 v = acc[cf];
    #pragma unroll
    for (int r = 0; r < 16; r++) {
      const int row = rowb + (r & 3) + 8 * (r >> 2);
      if (row >= M) continue;
      float val = v[r] + bv;
      if (col < 87) out[(size_t)row * 87 + col] = val;
      else if (col < 93) out2[(size_t)row * 6 + (col - 87)] = val;
    }
  }
}

// ---------------------------------------------------------------------------
// gemm3_k: GEMM with FUSED A-GENERATION (r12-proven).
// NIN=2 MODE_EMB: node init. NIN=3 MODE_EBF16: edge MLP in CSR order
// (row p pulls eattr[eids[p]]; sequential e_csr writes).
// ---------------------------------------------------------------------------
template<int NIN, int MODE>
__global__ __launch_bounds__(256, 3)
void gemm3_k(const float* __restrict__ in0, const float* __restrict__ in1,
             const float* __restrict__ aw, const float* __restrict__ ab1,
             const bf16_t* __restrict__ Wt, const float* __restrict__ bias,
             void* outv, int M, const int* __restrict__ z,
             const float* __restrict__ emb)
{
  __shared__ bf16_t As2[64 * 32];
  __shared__ bf16_t Bs2[320 * 32];

  const int tid = threadIdx.x;
  const int wave = tid >> 6;
  const int lane = tid & 63;
  const int lhalf = lane >> 5;
  const int l31 = lane & 31;
  const int m0 = blockIdx.x * 64;

  const int lr = lane >> 2;
  const int lu = lane & 3;

  const int ar = wave * 16 + lr;
  const int au = lu ^ ((ar >> 1) & 3);
  int arow = m0 + ar; if (arow >= M) arow = M - 1;

  float a0, a1, a2 = 0.f;
  if constexpr (NIN == 2) {
    a0 = in0[arow]; a1 = in1[arow];
  } else {
    long erow = arow;
    if constexpr (MODE == MODE_EBF16) erow = z[arow];  // CSR position -> edge id
    a0 = in0[erow * 3 + 0];
    a1 = in0[erow * 3 + 1];
    a2 = in0[erow * 3 + 2];
  }

  const bf16_t* bsrc[5];
  #pragma unroll
  for (int c = 0; c < 5; c++) {
    int q = wave * 5 + c;
    int bn = q * 16 + lr;
    int bu = lu ^ ((bn >> 1) & 3);
    bsrc[c] = Wt + (size_t)bn * LDP + bu * 8;
  }

  f32x16 acc[5] = {};

  for (int k0 = 0; k0 < LDP; k0 += 32) {
    {
      const int cb = k0 + au * 8;
      bf16x8 v;
      #pragma unroll
      for (int j = 0; j < 8; j++) {
        const int cc = cb + j;
        float t = 0.f;
        if (cc < DD) {
          t = a0 * aw[cc] + a1 * aw[DD + cc];
          if constexpr (NIN == 3) t += a2 * aw[2 * DD + cc];
          t = fmaxf(t + ab1[cc], 0.f);
        }
        v[j] = (bf16_t)t;
      }
      *(bf16x8*)&As2[ar * 32 + lu * 8] = v;
    }
    #pragma unroll
    for (int c = 0; c < 5; c++)
      gload16(bsrc[c] + k0, Bs2 + (wave * 5 + c) * 512);
    __syncthreads();
    #pragma unroll
    for (int ks = 0; ks < 2; ks++) {
      const int j0 = ks * 2 + lhalf;
      const int ra = (wave & 1) * 32 + l31;
      bf16x8 af = *(const bf16x8*)&As2[ra * 32 + ((j0 ^ ((ra >> 1) & 3)) * 8)];
      #pragma unroll
      for (int cf = 0; cf < 5; cf++) {
        const int bn = (wave >> 1) * 160 + cf * 32 + l31;
        bf16x8 bv = *(const bf16x8*)&Bs2[bn * 32 + ((j0 ^ ((bn >> 1) & 3)) * 8)];
        acc[cf] = __builtin_amdgcn_mfma_f32_32x32x16_bf16(af, bv, acc[cf], 0, 0, 0);
      }
    }
    __syncthreads();
  }

  const int colb = (wave >> 1) * 160;
  const int rowb = m0 + (wave & 1) * 32 + 4 * lhalf;
  #pragma unroll
  for (int cf = 0; cf < 5; cf++) {
    const int col = colb + cf * 32 + l31;
    const float bv = (col < DD) ? bias[col] : 0.f;
    f32x16 v = acc[cf];
    #pragma unroll
    for (int r = 0; r < 16; r++) {
      const int row = rowb + (r & 3) + 8 * (r >> 2);
      if (row >= M) continue;
      float val = v[r] + bv;
      if constexpr (MODE == MODE_EBF16) {
        if (col < EST)
          ((bf16_t*)outv)[(size_t)row * EST + col] = (bf16_t)val;
      } else if constexpr (MODE == MODE_EPERM) {
        if (col < EST)
          ((bf16_t*)outv)[(size_t)z[row] * EST + col] = (bf16_t)val;
      } else {  // MODE_EMB
        float add = (col < DD) ? emb[(size_t)z[row] * DD + col] : 0.f;
        ((bf16_t*)outv)[(size_t)row * LDP + col] = (bf16_t)(val + add);
      }
    }
  }
}

// ---------------------------------------------------------------------------
// gemm_mlp: fused per-layer MLP (r8/r12-proven, 144us). LDS-staged B via
// gload_lds (r10 proved direct-B from global thrashes L2; r13 proved pulling
// the gather inside kills its TLP). t-tile stays in LDS; in-place over g is
// safe. W2 = W1t + 5*WSLOT.
// ---------------------------------------------------------------------------
__global__ __launch_bounds__(256, 2)
void gemm_mlp(const bf16_t* Gv, const bf16_t* __restrict__ W1t,
              const float* __restrict__ b1, const float* __restrict__ b2,
              bf16_t* uout, int M, float* __restrict__ sums)
{
  __shared__ bf16_t As2[64 * 32];
  __shared__ bf16_t Bs2[320 * 32];
  __shared__ bf16_t Ts[64 * TLD];
  __shared__ float  red[2 * 320];

  const int tid = threadIdx.x;
  const int wave = tid >> 6;
  const int lane = tid & 63;
  const int lhalf = lane >> 5;
  const int l31 = lane & 31;
  const int m0 = blockIdx.x * 64;

  const int lr = lane >> 2;
  const int lu = lane & 3;

  const int ar = wave * 16 + lr;
  const int au = lu ^ ((ar >> 1) & 3);
  int arow = m0 + ar; if (arow >= M) arow = M - 1;
  const bf16_t* asrc = Gv + (size_t)arow * LDP + au * 8;

  const bf16_t* bsrc[5];
  #pragma unroll
  for (int c = 0; c < 5; c++) {
    int q = wave * 5 + c;
    int bn = q * 16 + lr;
    int bu = lu ^ ((bn >> 1) & 3);
    bsrc[c] = W1t + (size_t)bn * LDP + bu * 8;
  }

  f32x16 acc[5] = {};
  const int colb = (wave >> 1) * 160;
  const int lrowb = (wave & 1) * 32 + 4 * lhalf;

  // GEMM1: t = relu(g @ W1 + b1)
  for (int k0 = 0; k0 < LDP; k0 += 32) {
    gload16(asrc + k0, As2 + wave * 512);
    #pragma unroll
    for (int c = 0; c < 5; c++)
      gload16(bsrc[c] + k0, Bs2 + (wave * 5 + c) * 512);
    __syncthreads();
    #pragma unroll
    for (int ks = 0; ks < 2; ks++) {
      const int j0 = ks * 2 + lhalf;
      const int ra = (wave & 1) * 32 + l31;
      bf16x8 af = *(const bf16x8*)&As2[ra * 32 + ((j0 ^ ((ra >> 1) & 3)) * 8)];
      #pragma unroll
      for (int cf = 0; cf < 5; cf++) {
        const int bn = (wave >> 1) * 160 + cf * 32 + l31;
        bf16x8 bv = *(const bf16x8*)&Bs2[bn * 32 + ((j0 ^ ((bn >> 1) & 3)) * 8)];
        acc[cf] = __builtin_amdgcn_mfma_f32_32x32x16_bf16(af, bv, acc[cf], 0, 0, 0);
      }
    }
    __syncthreads();
  }

  // epilogue 1 -> Ts (relu + bf16 round; W1 pad cols zero -> t pad = 0)
  #pragma unroll
  for (int cf = 0; cf < 5; cf++) {
    const int col = colb + cf * 32 + l31;
    const float bv1 = (col < DD) ? b1[col] : 0.f;
    f32x16 v = acc[cf];
    #pragma unroll
    for (int r = 0; r < 16; r++) {
      const int lrow = lrowb + (r & 3) + 8 * (r >> 2);
      Ts[lrow * TLD + col] = (bf16_t)fmaxf(v[r] + bv1, 0.f);
    }
  }
  {
    f32x16 zz = {};
    #pragma unroll
    for (int cf = 0; cf < 5; cf++) acc[cf] = zz;
  }

  // GEMM2: u = t @ W2 + b2  (first __syncthreads below publishes Ts)
  for (int k0 = 0; k0 < LDP; k0 += 32) {
    #pragma unroll
    for (int c = 0; c < 5; c++)
      gload16(bsrc[c] + (size_t)5 * WSLOT + k0, Bs2 + (wave * 5 + c) * 512);
    __syncthreads();
    #pragma unroll
    for (int ks = 0; ks < 2; ks++) {
      const int j0 = ks * 2 + lhalf;
      const int ra = (wave & 1) * 32 + l31;
      bf16x8 af = *(const bf16x8*)&Ts[ra * TLD + k0 + j0 * 8];
      #pragma unroll
      for (int cf = 0; cf < 5; cf++) {
        const int bn = (wave >> 1) * 160 + cf * 32 + l31;
        bf16x8 bv = *(const bf16x8*)&Bs2[bn * 32 + ((j0 ^ ((bn >> 1) & 3)) * 8)];
        acc[cf] = __builtin_amdgcn_mfma_f32_32x32x16_bf16(af, bv, acc[cf], 0, 0, 0);
      }
    }
    __syncthreads();
  }

  // epilogue 2: bias2, bf16 u, BN sums (fp32 pre-rounding), block-combined atomics
  float s1[5], s2[5];
  #pragma unroll
  for (int i = 0; i < 5; i++) { s1[i] = 0.f; s2[i] = 0.f; }
  const int rowb = m0 + lrowb;
  #pragma unroll
  for (int cf = 0; cf < 5; cf++) {
    const int col = colb + cf * 32 + l31;
    const float bv2 = (col < DD) ? b2[col] : 0.f;
    f32x16 v = acc[cf];
    #pragma unroll
    for (int r = 0; r < 16; r++) {
      const int row = rowb + (r & 3) + 8 * (r >> 2);
      if (row >= M) continue;
      float val = v[r] + bv2;
      uout[(size_t)row * LDP + col] = (bf16_t)val;
      s1[cf] += val; s2[cf] += val * val;
    }
  }
  float t1[5], t2[5];
  #pragma unroll
  for (int cf = 0; cf < 5; cf++) {
    t1[cf] = s1[cf] + __shfl_down(s1[cf], 32);
    t2[cf] = s2[cf] + __shfl_down(s2[cf], 32);
  }
  if ((wave & 1) == 0 && lhalf == 0) {
    #pragma unroll
    for (int cf = 0; cf < 5; cf++) {
      const int col = colb + cf * 32 + l31;
      red[col] = t1[cf];
      red[320 + col] = t2[cf];
    }
  }
  __syncthreads();
  if ((wave & 1) == 1 && lhalf == 0) {
    #pragma unroll
    for (int cf = 0; cf < 5; cf++) {
      const int col = colb + cf * 32 + l31;
      if (col < DD) {
        atomicAdd(&sums[col], t1[cf] + red[col]);
        atomicAdd(&sums[LDP + col], t2[cf] + red[320 + col]);
      }
    }
  }
}

// ---------------------------------------------------------------------------
// old gemm_k: fallback (scatter) path only
// ---------------------------------------------------------------------------
template<bool ABF16, int MODE>
__global__ __launch_bounds__(256, 2)
void gemm_k(const void* Av, const bf16_t* __restrict__ Wt,
            const float* __restrict__ bias, void* outv, int M,
            const int* __restrict__ z, const float* __restrict__ emb,
            float* __restrict__ out2, const float* __restrict__ bias2)
{
  __shared__ bf16_t As[128 * 40];
  __shared__ bf16_t Bs[320 * 40];
  const int tid = threadIdx.x;
  const int wave = tid >> 6;
  const int lane = tid & 63;
  const int lhalf = lane >> 5;
  const int l31 = lane & 31;
  const int m0 = blockIdx.x * 128;

  f32x16 acc[2][5] = {};

  for (int k0 = 0; k0 < LDP; k0 += 32) {
    #pragma unroll
    for (int i = 0; i < 5; i++) {
      int idx = tid + i * 256;
      int n = idx >> 2, cv = idx & 3;
      *(bf16x8*)&Bs[n * 40 + cv * 8] =
          *(const bf16x8*)(Wt + (size_t)n * LDP + k0 + cv * 8);
    }
    if constexpr (ABF16) {
      const bf16_t* A = (const bf16_t*)Av;
      #pragma unroll
      for (int i = 0; i < 2; i++) {
        int r = (tid >> 2) + i * 64;
        int cv = tid & 3;
        int row = m0 + r;
        bf16x8 v = {};
        if (row < M) v = *(const bf16x8*)(A + (size_t)row * LDP + k0 + cv * 8);
        *(bf16x8*)&As[r * 40 + cv * 8] = v;
      }
    } else {
      const float* A = (const float*)Av;
      #pragma unroll
      for (int i = 0; i < 4; i++) {
        int r = (tid >> 3) + i * 32;
        int cv = tid & 7;
        int row = m0 + r;
        float fx = 0.f, fy = 0.f, fz2 = 0.f, fw = 0.f;
        if (row < M) {
          const float4 f = *(const float4*)(A + (size_t)row * LDP + k0 + cv * 4);
          fx = f.x; fy = f.y; fz2 = f.z; fw = f.w;
        }
        bf16x4 v;
        v.x = (bf16_t)fx; v.y = (bf16_t)fy; v.z = (bf16_t)fz2; v.w = (bf16_t)fw;
        *(bf16x4*)&As[r * 40 + cv * 4] = v;
      }
    }
    __syncthreads();
    #pragma unroll
    for (int ks = 0; ks < 2; ks++) {
      const int kk = ks * 16 + lhalf * 8;
      bf16x8 af0 = *(const bf16x8*)&As[((wave & 1) * 64 + 0  + l31) * 40 + kk];
      bf16x8 af1 = *(const bf16x8*)&As[((wave & 1) * 64 + 32 + l31) * 40 + kk];
      #pragma unroll
      for (int cf = 0; cf < 5; cf++) {
        bf16x8 bv = *(const bf16x8*)&Bs[((wave >> 1) * 160 + cf * 32 + l31) * 40 + kk];
        acc[0][cf] = __builtin_amdgcn_mfma_f32_32x32x16_bf16(af0, bv, acc[0][cf], 0, 0, 0);
        acc[1][cf] = __builtin_amdgcn_mfma_f32_32x32x16_bf16(af1, bv, acc[1][cf], 0, 0, 0);
      }
    }
    __syncthreads();
  }

  const int colb = (wave >> 1) * 160;
  float s1[5], s2[5];
  #pragma unroll
  for (int i = 0; i < 5; i++) { s1[i] = 0.f; s2[i] = 0.f; }

  #pragma unroll
  for (int rf = 0; rf < 2; rf++) {
    const int rowb = m0 + (wave & 1) * 64 + rf * 32 + 4 * lhalf;
    #pragma unroll
    for (int cf = 0; cf < 5; cf++) {
      const int col = colb + cf * 32 + l31;
      float bv;
      if constexpr (MODE == MODE_HEAD) {
        bv = (col < 87) ? bias[col] : (col < 93 ? bias2[col - 87] : 0.f);
      } else {
        bv = (col < DD) ? bias[col] : 0.f;
      }
      f32x16 v = acc[rf][cf];
      #pragma unroll
      for (int r = 0; r < 16; r++) {
        const int row = rowb + (r & 3) + 8 * (r >> 2);
        if (row >= M) continue;
        float val = v[r] + bv;
        if constexpr (MODE == MODE_F32S) {
          ((float*)outv)[(size_t)row * LDP + col] = val;
          s1[cf] += val; s2[cf] += val * val;
        } else if constexpr (MODE == MODE_BF16_RELU) {
          ((bf16_t*)outv)[(size_t)row * LDP + col] = (bf16_t)fmaxf(val, 0.f);
        } else if constexpr (MODE == MODE_BF16) {
          ((bf16_t*)outv)[(size_t)row * LDP + col] = (bf16_t)val;
        } else if constexpr (MODE == MODE_EMB) {
          float add = (col < DD) ? emb[(size_t)z[row] * DD + col] : 0.f;
          ((bf16_t*)outv)[(size_t)row * LDP + col] = (bf16_t)(val + add);
        } else {  // MODE_HEAD
          if (col < 87) ((float*)outv)[(size_t)row * 87 + col] = val;
          else if (col < 93) out2[(size_t)row * 6 + (col - 87)] = val;
        }
      }
    }
  }

  if constexpr (MODE == MODE_F32S) {
    #pragma unroll
    for (int cf = 0; cf < 5; cf++) {
      const int col = colb + cf * 32 + l31;
      float o1 = __shfl_down(s1[cf], 32);
      float o2 = __shfl_down(s2[cf], 32);
      if (lhalf == 0 && col < DD) {
        atomicAdd(&out2[col], s1[cf] + o1);
        atomicAdd(&out2[LDP + col], s2[cf] + o2);
      }
    }
  }
}

__global__ void stage1_node(const float* __restrict__ ch, const float* __restrict__ fc,
                            const float* __restrict__ w1, const float* __restrict__ b1,
                            bf16_t* __restrict__ t, int n) {
  int idx = blockIdx.x * 256 + threadIdx.x;
  if (idx >= n * LDP) return;
  int i = idx / LDP;
  int c = idx - i * LDP;
  float v = 0.f;
  if (c < DD) v = fmaxf(ch[i] * w1[c] + fc[i] * w1[DD + c] + b1[c], 0.f);
  t[idx] = (bf16_t)v;
}

__global__ void stage1_edge(const float* __restrict__ ea,
                            const float* __restrict__ w1, const float* __restrict__ b1,
                            bf16_t* __restrict__ t, int n) {
  int idx = blockIdx.x * 256 + threadIdx.x;
  if (idx >= n * LDP) return;
  int i = idx / LDP;
  int c = idx - i * LDP;
  float v = 0.f;
  if (c < DD) {
    float a0 = ea[(long)i * 3 + 0], a1 = ea[(long)i * 3 + 1], a2 = ea[(long)i * 3 + 2];
    v = fmaxf(a0 * w1[c] + a1 * w1[DD + c] + a2 * w1[2 * DD + c] + b1[c], 0.f);
  }
  t[idx] = (bf16_t)v;
}

// ---------------- CSR build (once per launch; lives in d_out scratch) ----------------
__global__ void csr_zero(int* __restrict__ p, int n) {
  int i = blockIdx.x * 256 + threadIdx.x;
  if (i < n) p[i] = 0;
}
__global__ void csr_hist(const int* __restrict__ dst, int* __restrict__ cnt, int E) {
  int e = blockIdx.x * 256 + threadIdx.x;
  if (e < E) atomicAdd(&cnt[dst[e]], 1);
}
__global__ void csr_part(const int* __restrict__ cnt, int* __restrict__ psum, int n) {
  __shared__ int wsum[4];
  int b = blockIdx.x, t = threadIdx.x;
  int i = b * 256 + t;
  int v = (i < n) ? cnt[i] : 0;
  #pragma unroll
  for (int o = 32; o > 0; o >>= 1) v += __shfl_down(v, o);
  if ((t & 63) == 0) wsum[t >> 6] = v;
  __syncthreads();
  if (t == 0) psum[b] = wsum[0] + wsum[1] + wsum[2] + wsum[3];
}
__global__ void csr_scan_small(int* __restrict__ psum, int nb) {
  if (threadIdx.x == 0) {
    int acc = 0;
    for (int i = 0; i < nb; i++) { int v = psum[i]; psum[i] = acc; acc += v; }
    psum[nb] = acc;
  }
}
__global__ void csr_scan_final(const int* __restrict__ cnt, const int* __restrict__ psum,
                               int* __restrict__ rowptr, int* __restrict__ cursor, int n) {
  __shared__ int sh[256];
  int b = blockIdx.x, t = threadIdx.x;
  int i = b * 256 + t;
  sh[t] = (i < n) ? cnt[i] : 0;
  __syncthreads();
  int s = psum[b];
  for (int j = 0; j < t; j++) s += sh[j];
  if (i <= n) {
    rowptr[i] = s;
    if (i < n) cursor[i] = s;
  }
}
__global__ void csr_fill(const int* __restrict__ dst, int* __restrict__ cursor,
                         int* __restrict__ eids, int E) {
  int e = blockIdx.x * 256 + threadIdx.x;
  if (e < E) { int p = atomicAdd(&cursor[dst[e]], 1); eids[p] = e; }
}
__global__ void csr_pos_src(const int* __restrict__ eids, const int* __restrict__ src,
                            int* __restrict__ pos, int* __restrict__ src_csr, int E) {
  int p = blockIdx.x * 256 + threadIdx.x;
  if (p < E) { int e = eids[p]; pos[e] = p; src_csr[p] = src[e]; }
}

// ---------------------------------------------------------------------------
// gather_bn: g[i,:] = f(R[i,:]) + sum_p relu(f(R[src,:]) + e_csr[p,:]),
// f(x) = BN? relu(x*a+b) : x.  8 cols/thread (40 groups/node) — r8/r12-proven.
// (r13 proved pulling this into the GEMM kills its TLP/L2-reuse.)
// ---------------------------------------------------------------------------
template<bool BN>
__global__ void gather_bn(const bf16_t* __restrict__ R, const bf16_t* __restrict__ e,
                          const int* __restrict__ src_csr, const int* __restrict__ rowptr,
                          const float* __restrict__ ab, bf16_t* __restrict__ g, int N) {
  long idx = (long)blockIdx.x * 256 + threadIdx.x;
  if (idx >= (long)N * 40) return;
  int i = (int)(idx / 40);
  int cg = (int)(idx - (long)i * 40);
  int c = cg * 8;
  if (cg >= 38) {  // pad cols 304..319
    bf16x8 zz = {};
    *(bf16x8*)(g + (size_t)i * LDP + c) = zz;
    return;
  }
  float a_[8], b_[8];
  if constexpr (BN) {
    #pragma unroll
    for (int j = 0; j < 8; j++) {
      bool v = (c + j) < DD;
      a_[j] = v ? ab[c + j] : 0.f;
      b_[j] = v ? ab[LDP + c + j] : 0.f;
    }
  }
  int r0 = rowptr[i], r1 = rowptr[i + 1];
  bf16x8 hv = *(const bf16x8*)(R + (size_t)i * LDP + c);
  float acc[8];
  #pragma unroll
  for (int j = 0; j < 8; j++) {
    float x = (float)hv[j];
    if constexpr (BN) x = fmaxf(x * a_[j] + b_[j], 0.f);
    acc[j] = x;
  }
  if (r0 < r1) {
    int s = src_csr[r0];
    for (int r = r0; r < r1;) {
      bf16x8 a = *(const bf16x8*)(R + (size_t)s * LDP + c);
      bf16x8 ev = *(const bf16x8*)(e + (size_t)r * EST + c);
      ++r;
      if (r < r1) s = src_csr[r];  // prefetch next src row id
      #pragma unroll
      for (int j = 0; j < 8; j++) {
        float x = (float)a[j];
        if constexpr (BN) x = fmaxf(x * a_[j] + b_[j], 0.f);
        acc[j] += fmaxf(x + (float)ev[j], 0.f);
      }
    }
  }
  bf16x8 o;
  #pragma unroll
  for (int j = 0; j < 8; j++) o[j] = (bf16_t)acc[j];
  *(bf16x8*)(g + (size_t)i * LDP + c) = o;
}

// ---------------- fallback-path kernels (chunked scatter; unchanged) ----------------
__global__ void init_hh(const bf16_t* __restrict__ h, float* __restrict__ hh, int total) {
  int idx = blockIdx.x * 256 + threadIdx.x;
  if (idx >= total) return;
  hh[idx] = (float)h[idx];
}

__global__ void scatter_k(const bf16_t* __restrict__ h, const bf16_t* __restrict__ e,
                          const int* __restrict__ src, const int* __restrict__ dst,
                          float* __restrict__ hh, int E) {
  int idx = blockIdx.x * 256 + threadIdx.x;
  if (idx >= E * 75) return;
  int ed = idx / 75;
  int q = idx - ed * 75;
  int s = src[ed], d = dst[ed];
  const bf16x4 hv = *(const bf16x4*)(h + (size_t)s * LDP + q * 4);
  const bf16x4 ev = *(const bf16x4*)(e + (size_t)ed * LDP + q * 4);
  float* o = hh + (size_t)d * LDP + q * 4;
  atomicAdd(o + 0, fmaxf((float)hv.x + (float)ev.x, 0.f));
  atomicAdd(o + 1, fmaxf((float)hv.y + (float)ev.y, 0.f));
  atomicAdd(o + 2, fmaxf((float)hv.z + (float)ev.z, 0.f));
  atomicAdd(o + 3, fmaxf((float)hv.w + (float)ev.w, 0.f));
}

__global__ void zero_sums(float* __restrict__ sums) { sums[threadIdx.x] = 0.f; }

// reads per-column sums -> writes ab, then RE-ZEROS sums for the next layer
__global__ void bn_final(float* __restrict__ sums, const float* __restrict__ gamma,
                         const float* __restrict__ beta, float* __restrict__ ab, int n) {
  int c = threadIdx.x;
  if (c >= LDP) return;
  float s1 = sums[c], s2 = sums[LDP + c];
  sums[c] = 0.f;
  sums[LDP + c] = 0.f;
  if (c >= DD) return;
  float inv_n = 1.f / (float)n;
  float mean = s1 * inv_n;
  float var = s2 * inv_n - mean * mean;  // biased var (torch/jnp)
  float a = gamma[c] * rsqrtf(fmaxf(var, 0.f) + 1e-5f);
  ab[c] = a;
  ab[LDP + c] = beta[c] - mean * a;
}

__global__ void bn_apply(float* u, const float* __restrict__ ab,
                         bf16_t* __restrict__ h, int total) {
  int idx = blockIdx.x * 256 + threadIdx.x;
  if (idx >= total) return;
  int c = idx % LDP;
  float v = 0.f;
  if (c < DD) v = fmaxf(u[idx] * ab[c] + ab[LDP + c], 0.f);
  h[idx] = (bf16_t)v;
  u[idx] = v;
}

extern "C" void kernel_launch(void* const* d_in, const int* in_sizes, int n_in,
                              void* d_out, int out_size, void* d_ws, size_t ws_size,
                              hipStream_t stream) {
  const int*   z        = (const int*)d_in[0];
  const float* chir     = (const float*)d_in[1];
  const float* fchg     = (const float*)d_in[2];
  const int*   eidx     = (const int*)d_in[3];
  const float* eattr    = (const float*)d_in[4];
  const float* atom_emb = (const float*)d_in[5];
  const float* nap_w1   = (const float*)d_in[6];
  const float* nap_b1   = (const float*)d_in[7];
  const float* nap_w2   = (const float*)d_in[8];
  const float* nap_b2   = (const float*)d_in[9];
  const float* ee_w1    = (const float*)d_in[10];
  const float* ee_b1    = (const float*)d_in[11];
  const float* ee_w2    = (const float*)d_in[12];
  const float* ee_b2    = (const float*)d_in[13];
  const float* gnn_w1   = (const float*)d_in[14];
  const float* gnn_b1   = (const float*)d_in[15];
  const float* gnn_w2   = (const float*)d_in[16];
  const float* gnn_b2   = (const float*)d_in[17];
  const float* bn_gamma = (const float*)d_in[18];
  const float* bn_beta  = (const float*)d_in[19];
  const float* ah_w     = (const float*)d_in[20];
  const float* ah_b     = (const float*)d_in[21];
  const float* ch_w     = (const float*)d_in[22];
  const float* ch_b     = (const float*)d_in[23];

  const int N = in_sizes[0];
  const int E = in_sizes[3] / 2;
  const int* src = eidx;
  const int* dst = eidx + E;

  char* ws = (char*)d_ws;
  size_t off = 0;
  auto take = [&](size_t bytes) -> void* {
    void* p = ws + off;
    off = (off + bytes + 255) & ~(size_t)255;
    return p;
  };
  auto alignup = [](size_t x) { return (x + 255) & ~(size_t)255; };

  bf16_t* wt12 = (bf16_t*)take((size_t)12 * WSLOT * 2);
  bf16_t* wtH  = (bf16_t*)take((size_t)WSLOT * 2);
  float*  sums = (float*)take((size_t)2 * LDP * 4);
  float*  ab   = (float*)take((size_t)2 * LDP * 4);
  bf16_t* h    = (bf16_t*)take((size_t)N * LDP * 2);   // bf16 buffer (ping)
  const size_t head_end = off;

  // fused tier: proven-fit 252.27MB layout: h + G + e_csr
  const size_t u16_b = (size_t)N * LDP * 2;
  const size_t e_b   = (size_t)E * EST * 2 + 256;
  const size_t need1 = head_end + alignup(u16_b) + alignup(e_b);
  int tier = (ws_size >= need1) ? 1 : 0;

  bf16_t* G      = nullptr;   // bf16 buffer (pong)
  bf16_t* e_csr  = nullptr;
  float*  hh     = nullptr;   // fallback fp32 aggregate
  bf16_t* echunk = nullptr;
  int EC = 0;
  if (tier) {
    G     = (bf16_t*)take(u16_b);
    e_csr = (bf16_t*)take(e_b);
  } else {
    hh = (float*)take((size_t)N * LDP * 4);
    const size_t base_end = off;
    if (ws_size < base_end) return;
    size_t slack = (ws_size > base_end + 256) ? (ws_size - base_end - 256) : 0;
    size_t ec_ws  = slack / (LDP * 2);
    size_t ec_out = ((size_t)out_size * 4) / (LDP * 2);
    size_t ec = ec_ws < ec_out ? ec_ws : ec_out;
    if (ec > (size_t)E) ec = E;
    ec &= ~(size_t)127;
    if (ec < 128) return;
    EC = (int)ec;
    echunk = (bf16_t*)take((size_t)EC * LDP * 2);
  }
  (void)n_in;

  Src12 s;
  s.p[0] = nap_w2; s.p[1] = ee_w2;
  for (int l = 0; l < 5; l++) {
    s.p[2 + l] = gnn_w1 + (size_t)l * DD * DD;
    s.p[7 + l] = gnn_w2 + (size_t)l * DD * DD;
  }
  prep_wt_all<<<dim3((WSLOT + 255) / 256, 12), 256, 0, stream>>>(s, wt12);
  prep_wt_head<<<(WSLOT + 255) / 256, 256, 0, stream>>>(ah_w, ch_w, wtH);

  const int gN = (N + 127) / 128;     // old-gemm grid (fallback)
  const int g2N = (N + 63) / 64;      // 64-row-tile grid

  if (tier) {
    // ---- CSR build in d_out scratch (legal until head GEMM) ----
    int* rowptr  = (int*)d_out;          // N+1
    int* src_csr = rowptr + (N + 1);     // E
    int* eids    = src_csr + E;          // E  (read by CSR-order edge GEMM)
    int* pos     = eids + E;             // E
    int* cnt     = pos + E;              // N
    int* cursor  = cnt + N;              // N
    int* psum    = cursor + N;           // NBLK+1
    const int NBLK = (N + 255) / 256;
    csr_zero<<<NBLK, 256, 0, stream>>>(cnt, N);
    csr_hist<<<(E + 255) / 256, 256, 0, stream>>>(dst, cnt, E);
    csr_part<<<NBLK, 256, 0, stream>>>(cnt, psum, N);
    csr_scan_small<<<1, 64, 0, stream>>>(psum, NBLK);
    csr_scan_final<<<(N + 256) / 256, 256, 0, stream>>>(cnt, psum, rowptr, cursor, N);
    csr_fill<<<(E + 255) / 256, 256, 0, stream>>>(dst, cursor, eids, E);
    csr_pos_src<<<(E + 255) / 256, 256, 0, stream>>>(eids, src, pos, src_csr, E);

    // edge features: ONE fused launch in CSR ORDER (r12-proven)
    gemm3_k<3, MODE_EBF16><<<(E + 63) / 64, 256, 0, stream>>>(
        eattr, nullptr, ee_w1, ee_b1, wt12 + (size_t)1 * WSLOT, ee_b2,
        e_csr, E, eids, nullptr);

    // node init fused: h = atom_emb[z] + relu(na@nap_w1+b1)@nap_w2+b2
    gemm3_k<2, MODE_EMB><<<g2N, 256, 0, stream>>>(
        chir, fchg, nap_w1, nap_b1, wt12 + (size_t)0 * WSLOT, nap_b2,
        h, N, z, atom_emb);

    // layers: gather(+inline BN) ping-pongs h <-> G; mlp in-place on gather out
    zero_sums<<<1, 2 * LDP, 0, stream>>>(sums);   // once; bn_final re-zeros
    const int gGat = (int)(((long)N * 40 + 255) / 256);
    for (int l = 0; l < 5; l++) {
      const bf16_t* gin = (l & 1) ? G : h;
      bf16_t* gout = (l & 1) ? h : G;
      if (l == 0)
        gather_bn<false><<<gGat, 256, 0, stream>>>(
            gin, e_csr, src_csr, rowptr, nullptr, gout, N);
      else
        gather_bn<true><<<gGat, 256, 0, stream>>>(
            gin, e_csr, src_csr, rowptr, ab, gout, N);
      gemm_mlp<<<g2N, 256, 0, stream>>>(
          gout, wt12 + (size_t)(2 + l) * WSLOT,
          gnn_b1 + (size_t)l * DD, gnn_b2 + (size_t)l * DD, gout, N, sums);
      bn_final<<<1, LDP, 0, stream>>>(sums, bn_gamma + (size_t)l * DD,
                                      bn_beta + (size_t)l * DD, ab, N);
    }
    // u4 lives in G (l=4 even) -> head with FUSED relu(BN(.)) A-gen, 128x96 tile
    gemm_hd2<<<(N + 127) / 128, 256, 0, stream>>>(
        G, ab, wtH, ah_b, (float*)d_out, N,
        (float*)d_out + (size_t)N * 87, ch_b);
  } else {
    // -------- fallback: original chunked scatter path (unchanged) --------
    stage1_node<<<((long)N * LDP + 255) / 256, 256, 0, stream>>>(chir, fchg, nap_w1, nap_b1, h, N);
    gemm_k<true, MODE_EMB><<<gN, 256, 0, stream>>>(
        h, wt12 + (size_t)0 * WSLOT, nap_b2, h, N, z, atom_emb, nullptr, nullptr);

    for (int l = 0; l < 5; l++) {
      if (l == 0)
        init_hh<<<((long)N * LDP + 255) / 256, 256, 0, stream>>>(h, hh, N * LDP);
      bf16_t* estage = (bf16_t*)d_out;  // legal scratch until final head GEMM
      for (int c0 = 0; c0 < E; c0 += EC) {
        int curn = (E - c0 < EC) ? (E - c0) : EC;
        stage1_edge<<<((long)curn * LDP + 255) / 256, 256, 0, stream>>>(
            eattr + (size_t)c0 * 3, ee_w1, ee_b1, estage, curn);
        gemm_k<true, MODE_BF16><<<(curn + 127) / 128, 256, 0, stream>>>(
            estage, wt12 + (size_t)1 * WSLOT, ee_b2, echunk, curn,
            nullptr, nullptr, nullptr, nullptr);
        scatter_k<<<((long)curn * 75 + 255) / 256, 256, 0, stream>>>(
            h, echunk, src + c0, dst + c0, hh, curn);
      }
      gemm_k<false, MODE_BF16_RELU><<<gN, 256, 0, stream>>>(
          hh, wt12 + (size_t)(2 + l) * WSLOT, gnn_b1 + (size_t)l * DD, h, N,
          nullptr, nullptr, nullptr, nullptr);
      zero_sums<<<1, 2 * LDP, 0, stream>>>(sums);
      gemm_k<true, MODE_F32S><<<gN, 256, 0, stream>>>(
          h, wt12 + (size_t)(7 + l) * WSLOT, gnn_b2 + (size_t)l * DD, hh, N,
          nullptr, nullptr, sums, nullptr);
      bn_final<<<1, LDP, 0, stream>>>(sums, bn_gamma + (size_t)l * DD, bn_beta + (size_t)l * DD, ab, N);
      bn_apply<<<((long)N * LDP + 255) / 256, 256, 0, stream>>>(hh, ab, h, N * LDP);
    }

    gemm_k<true, MODE_HEAD><<<gN, 256, 0, stream>>>(
        h, wtH, ah_b, d_out, N, nullptr, nullptr, (float*)d_out + (size_t)N * 87, ch_b);
  }
}